// Round 1
// baseline (92.470 us; speedup 1.0000x reference)
//
#include <hip/hip_runtime.h>

#define NGT 256

__global__ __launch_bounds__(256) void roi_assign_kernel(
    const float* __restrict__ proposals,  // [N,4]
    const float* __restrict__ gt_boxes,   // [M,4]
    const int*   __restrict__ gt_labels,  // [M]
    float* __restrict__ out_labels,       // [N] (float-encoded ints)
    float* __restrict__ out_deltas,       // [N,4]
    int N, int M)
{
    __shared__ float s_g[NGT * 4];
    __shared__ float s_area[NGT];

    // cooperative stage of GT boxes + areas into LDS
    for (int t = threadIdx.x; t < M * 4; t += blockDim.x) s_g[t] = gt_boxes[t];
    __syncthreads();
    for (int t = threadIdx.x; t < M; t += blockDim.x) {
        float x1 = s_g[t * 4 + 0], y1 = s_g[t * 4 + 1];
        float x2 = s_g[t * 4 + 2], y2 = s_g[t * 4 + 3];
        s_area[t] = (x2 - x1) * (y2 - y1);
    }
    __syncthreads();

    int i = blockIdx.x * blockDim.x + threadIdx.x;
    if (i >= N) return;

    float4 p = reinterpret_cast<const float4*>(proposals)[i];
    float area_a = (p.z - p.x) * (p.w - p.y);

    // best-so-far tracked as (inter, union) pair; compare via cross-mult
    // (union > 0 always: boxes have min size 8). Init (-1, 1): any j=0
    // candidate wins since inter_0 >= 0 > -union_0.
    float best_inter = -1.0f;
    float best_union = 1.0f;
    int   best_idx   = 0;

#pragma unroll 8
    for (int j = 0; j < NGT; ++j) {
        float gx1 = s_g[j * 4 + 0], gy1 = s_g[j * 4 + 1];
        float gx2 = s_g[j * 4 + 2], gy2 = s_g[j * 4 + 3];
        float lx = fmaxf(p.x, gx1), ly = fmaxf(p.y, gy1);
        float rx = fminf(p.z, gx2), ry = fminf(p.w, gy2);
        float w = fmaxf(rx - lx, 0.0f);
        float h = fmaxf(ry - ly, 0.0f);
        float inter = w * h;
        float uni = area_a + s_area[j] - inter;
        // iou_j > iou_best  <=>  inter_j * union_best > inter_best * union_j
        bool upd = (inter * best_union) > (best_inter * uni);
        best_inter = upd ? inter : best_inter;
        best_union = upd ? uni   : best_union;
        best_idx   = upd ? j     : best_idx;
    }

    float max_iou = best_inter / best_union;   // single IEEE f32 division
    bool pos = (max_iou >= 0.5f);

    int lbl = gt_labels[best_idx];
    out_labels[i] = pos ? (float)lbl : 0.0f;

    // box-delta encode against matched gt
    float gx1 = s_g[best_idx * 4 + 0], gy1 = s_g[best_idx * 4 + 1];
    float gx2 = s_g[best_idx * 4 + 2], gy2 = s_g[best_idx * 4 + 3];

    float pw = p.z - p.x;
    float ph = p.w - p.y;
    float px = p.x + 0.5f * pw;
    float py = p.y + 0.5f * ph;
    float gw = gx2 - gx1;
    float gh = gy2 - gy1;
    float gx = gx1 + 0.5f * gw;
    float gy = gy1 + 0.5f * gh;

    float tx = (gx - px) / pw;
    float ty = (gy - py) / ph;
    float tw = logf(gw / pw);
    float th = logf(gh / ph);

    float4 d;
    if (pos) { d.x = tx; d.y = ty; d.z = tw; d.w = th; }
    else     { d.x = 0.f; d.y = 0.f; d.z = 0.f; d.w = 0.f; }
    reinterpret_cast<float4*>(out_deltas)[i] = d;
}

extern "C" void kernel_launch(void* const* d_in, const int* in_sizes, int n_in,
                              void* d_out, int out_size, void* d_ws, size_t ws_size,
                              hipStream_t stream) {
    const float* proposals = (const float*)d_in[0];
    const float* gt_boxes  = (const float*)d_in[1];
    const int*   gt_labels = (const int*)d_in[2];

    int N = in_sizes[0] / 4;   // 262144
    int M = in_sizes[1] / 4;   // 256

    float* out_labels = (float*)d_out;       // first N floats
    float* out_deltas = (float*)d_out + N;   // then N*4 floats

    dim3 block(256);
    dim3 grid((N + 255) / 256);
    roi_assign_kernel<<<grid, block, 0, stream>>>(
        proposals, gt_boxes, gt_labels, out_labels, out_deltas, N, M);
}